// Round 1
// baseline (506.137 us; speedup 1.0000x reference)
//
#include <hip/hip_runtime.h>

typedef __attribute__((ext_vector_type(8))) short bf16x8;
typedef __attribute__((ext_vector_type(4))) float f32x4;
typedef __attribute__((ext_vector_type(4))) short s16x4;
typedef unsigned short u16;

#define MFMA16(a,b,c) __builtin_amdgcn_mfma_f32_16x16x32_bf16((a),(b),(c),0,0,0)
#define L2E 1.4426950408889634f

__device__ __forceinline__ u16 f2bf(float f) {
    unsigned u = __float_as_uint(f);
    return (u16)((u + 0x7FFFu + ((u >> 16) & 1u)) >> 16);
}
__device__ __forceinline__ float bf2f(u16 h) {
    return __uint_as_float(((unsigned)h) << 16);
}

// ---------------- elementwise converts ----------------
__global__ __launch_bounds__(256) void split_kernel(const float* __restrict__ in,
                                                    u16* __restrict__ hi, u16* __restrict__ lo, int n4) {
    int i = blockIdx.x * 256 + threadIdx.x;
    if (i >= n4) return;
    f32x4 v = ((const f32x4*)in)[i];
    s16x4 h, l;
#pragma unroll
    for (int j = 0; j < 4; ++j) {
        u16 hh = f2bf(v[j]);
        h[j] = (short)hh;
        l[j] = (short)f2bf(v[j] - bf2f(hh));
    }
    ((s16x4*)hi)[i] = h;
    ((s16x4*)lo)[i] = l;
}

__global__ __launch_bounds__(256) void cvt_kernel(const float* __restrict__ in, u16* __restrict__ out, int n4) {
    int i = blockIdx.x * 256 + threadIdx.x;
    if (i >= n4) return;
    f32x4 v = ((const f32x4*)in)[i];
    s16x4 h;
#pragma unroll
    for (int j = 0; j < 4; ++j) h[j] = (short)f2bf(v[j]);
    ((s16x4*)out)[i] = h;
}

// ---------------- qkv GEMM: (8192x1024) x (3072x1024)^T, split-bf16 for q,k cols ----------------
__global__ __launch_bounds__(256) void qkv_gemm(const u16* __restrict__ xh, const u16* __restrict__ xl,
                                                const u16* __restrict__ wh, const u16* __restrict__ wl,
                                                float* __restrict__ qkv) {
    __shared__ u16 Ah[128 * 32], Al[128 * 32], Bh[128 * 32], Bl[128 * 32];
    const int mb = blockIdx.x / 24, nb = blockIdx.x % 24;
    const int m0 = mb * 128, n0 = nb * 128;
    const bool lo = (n0 < 2048);          // v third: plain bf16 is enough
    const int tid = threadIdx.x, lane = tid & 63, w = tid >> 6;
    const int wr = w >> 1, wc = w & 1;
    const int srow = tid >> 1, skc = (tid & 1) << 4;
    const u16* pah = xh + (m0 + srow) * 1024 + skc;
    const u16* pal = xl + (m0 + srow) * 1024 + skc;
    const u16* pbh = wh + (n0 + srow) * 1024 + skc;
    const u16* pbl = wl + (n0 + srow) * 1024 + skc;
    const int s0 = skc >> 3;
    const int wA0 = srow * 32 + (((s0    ) ^ (srow & 3)) << 3);
    const int wA1 = srow * 32 + (((s0 + 1) ^ (srow & 3)) << 3);
    f32x4 acc[4][4] = {};
    for (int k0 = 0; k0 < 1024; k0 += 32) {
        *(bf16x8*)&Ah[wA0] = *(const bf16x8*)(pah);
        *(bf16x8*)&Ah[wA1] = *(const bf16x8*)(pah + 8);
        *(bf16x8*)&Bh[wA0] = *(const bf16x8*)(pbh);
        *(bf16x8*)&Bh[wA1] = *(const bf16x8*)(pbh + 8);
        if (lo) {
            *(bf16x8*)&Al[wA0] = *(const bf16x8*)(pal);
            *(bf16x8*)&Al[wA1] = *(const bf16x8*)(pal + 8);
            *(bf16x8*)&Bl[wA0] = *(const bf16x8*)(pbl);
            *(bf16x8*)&Bl[wA1] = *(const bf16x8*)(pbl + 8);
        }
        pah += 32; pal += 32; pbh += 32; pbl += 32;
        __syncthreads();
        const int rsl = lane >> 4;
        bf16x8 a_h[4], a_l[4];
#pragma unroll
        for (int m = 0; m < 4; ++m) {
            int row = wr * 64 + m * 16 + (lane & 15);
            int off = row * 32 + ((rsl ^ (row & 3)) << 3);
            a_h[m] = *(const bf16x8*)&Ah[off];
            if (lo) a_l[m] = *(const bf16x8*)&Al[off];
        }
#pragma unroll
        for (int n = 0; n < 4; ++n) {
            int row = wc * 64 + n * 16 + (lane & 15);
            int off = row * 32 + ((rsl ^ (row & 3)) << 3);
            bf16x8 b_h = *(const bf16x8*)&Bh[off];
            if (lo) {
                bf16x8 b_l = *(const bf16x8*)&Bl[off];
#pragma unroll
                for (int m = 0; m < 4; ++m) {
                    acc[m][n] = MFMA16(a_h[m], b_h, acc[m][n]);
                    acc[m][n] = MFMA16(a_h[m], b_l, acc[m][n]);
                    acc[m][n] = MFMA16(a_l[m], b_h, acc[m][n]);
                }
            } else {
#pragma unroll
                for (int m = 0; m < 4; ++m) acc[m][n] = MFMA16(a_h[m], b_h, acc[m][n]);
            }
        }
        __syncthreads();
    }
#pragma unroll
    for (int m = 0; m < 4; ++m) {
        int rowb = m0 + wr * 64 + m * 16 + (lane >> 4) * 4;
#pragma unroll
        for (int n = 0; n < 4; ++n) {
            int col = n0 + wc * 64 + n * 16 + (lane & 15);
#pragma unroll
            for (int r = 0; r < 4; ++r)
                qkv[(size_t)(rowb + r) * 3072 + col] = acc[m][n][r];
        }
    }
}

// ---------------- rotary (cos/sin of q), split q',k', transpose v ----------------
__global__ __launch_bounds__(256) void rotary_split(const float* __restrict__ qkv,
                                                    u16* __restrict__ qh, u16* __restrict__ ql,
                                                    u16* __restrict__ kh, u16* __restrict__ kl,
                                                    u16* __restrict__ vt) {
    int rid = blockIdx.x * 4 + (threadIdx.x >> 6);
    int lane = threadIdx.x & 63;
    int b = rid >> 14, h = (rid >> 10) & 15, t = rid & 1023;
    const float* base = qkv + (size_t)(b * 1024 + t) * 3072 + h * 64 + lane;
    float q = base[0], k = base[1024], v = base[2048];
    float s, c;
    sincosf(q, &s, &c);
    int src = (lane < 32) ? (2 * lane + 1) : (2 * lane - 64);
    float qp = __shfl(q, src);
    float kp = __shfl(k, src);
    float rq = (lane < 32) ? -qp : qp;
    float rk = (lane < 32) ? -kp : kp;
    float q2 = q * c + rq * s;
    float k2 = k * c + rk * s;
    size_t oi = (size_t)((b * 16 + h) * 1024 + t) * 64 + lane;
    u16 qhh = f2bf(q2);
    qh[oi] = qhh; ql[oi] = f2bf(q2 - bf2f(qhh));
    u16 khh = f2bf(k2);
    kh[oi] = khh; kl[oi] = f2bf(k2 - bf2f(khh));
    vt[(size_t)((b * 16 + h) * 64 + lane) * 1024 + t] = f2bf(v);
}

// ---------------- flash attention, causal, scale=1.0, split-bf16 QK^T ----------------
__global__ __launch_bounds__(256) void attn_kernel(const u16* __restrict__ qh, const u16* __restrict__ ql,
                                                   const u16* __restrict__ kh, const u16* __restrict__ kl,
                                                   const u16* __restrict__ vt, u16* __restrict__ yb) {
    __shared__ u16 sQh[4096], sQl[4096], sKh[4096], sKl[4096], sV[4096], sP[4096];
    const int bh = blockIdx.x >> 4, qt = blockIdx.x & 15;
    const int b = bh >> 4, h = bh & 15;
    const int tid = threadIdx.x, lane = tid & 63, w = tid >> 6;
    const int q0 = qt * 64;
    const int srow = tid >> 2, sc = (tid & 3) << 4;
    const int ss0 = sc >> 3;
    const int wr0 = srow * 64 + (((ss0    ) ^ (srow & 7)) << 3);
    const int wr1 = srow * 64 + (((ss0 + 1) ^ (srow & 7)) << 3);
    {
        const u16* g  = qh + (size_t)(bh * 1024 + q0 + srow) * 64 + sc;
        const u16* g2 = ql + (size_t)(bh * 1024 + q0 + srow) * 64 + sc;
        *(bf16x8*)&sQh[wr0] = *(const bf16x8*)g;
        *(bf16x8*)&sQh[wr1] = *(const bf16x8*)(g + 8);
        *(bf16x8*)&sQl[wr0] = *(const bf16x8*)g2;
        *(bf16x8*)&sQl[wr1] = *(const bf16x8*)(g2 + 8);
    }
    __syncthreads();
    bf16x8 qfh[2], qfl[2];
    {
        int row = w * 16 + (lane & 15);
#pragma unroll
        for (int kk = 0; kk < 2; ++kk) {
            int sl = kk * 4 + (lane >> 4);
            int off = row * 64 + ((sl ^ (row & 7)) << 3);
            qfh[kk] = *(const bf16x8*)&sQh[off];
            qfl[kk] = *(const bf16x8*)&sQl[off];
        }
    }
    f32x4 accy[4] = {};
    float m_r[4], l_r[4];
#pragma unroll
    for (int r = 0; r < 4; ++r) { m_r[r] = -1e30f; l_r[r] = 0.f; }
    const u16* gkh = kh + (size_t)bh * 65536 + srow * 64 + sc;
    const u16* gkl = kl + (size_t)bh * 65536 + srow * 64 + sc;
    const u16* gv  = vt + (size_t)(bh * 64 + srow) * 1024 + sc;

    for (int kt = 0; kt <= qt; ++kt) {
        __syncthreads();
        {
            const u16* a  = gkh + kt * 4096;
            const u16* c2 = gkl + kt * 4096;
            const u16* vg = gv + kt * 64;
            *(bf16x8*)&sKh[wr0] = *(const bf16x8*)a;
            *(bf16x8*)&sKh[wr1] = *(const bf16x8*)(a + 8);
            *(bf16x8*)&sKl[wr0] = *(const bf16x8*)c2;
            *(bf16x8*)&sKl[wr1] = *(const bf16x8*)(c2 + 8);
            *(bf16x8*)&sV[wr0]  = *(const bf16x8*)vg;
            *(bf16x8*)&sV[wr1]  = *(const bf16x8*)(vg + 8);
        }
        __syncthreads();
        f32x4 s[4] = {};
#pragma unroll
        for (int n = 0; n < 4; ++n) {
            int krow = n * 16 + (lane & 15);
#pragma unroll
            for (int kk = 0; kk < 2; ++kk) {
                int sl = kk * 4 + (lane >> 4);
                int off = krow * 64 + ((sl ^ (krow & 7)) << 3);
                bf16x8 kbh = *(const bf16x8*)&sKh[off];
                bf16x8 kbl = *(const bf16x8*)&sKl[off];
                s[n] = MFMA16(qfh[kk], kbh, s[n]);
                s[n] = MFMA16(qfh[kk], kbl, s[n]);
                s[n] = MFMA16(qfl[kk], kbh, s[n]);
            }
        }
        if (kt == qt) {
            int colb = lane & 15;
            int rowb = w * 16 + (lane >> 4) * 4;
#pragma unroll
            for (int n = 0; n < 4; ++n)
#pragma unroll
                for (int r = 0; r < 4; ++r)
                    if (n * 16 + colb > rowb + r) s[n][r] = -1e30f;
        }
        float alpha[4];
#pragma unroll
        for (int r = 0; r < 4; ++r) {
            float mx = fmaxf(fmaxf(s[0][r], s[1][r]), fmaxf(s[2][r], s[3][r]));
            mx = fmaxf(mx, __shfl_xor(mx, 1));
            mx = fmaxf(mx, __shfl_xor(mx, 2));
            mx = fmaxf(mx, __shfl_xor(mx, 4));
            mx = fmaxf(mx, __shfl_xor(mx, 8));
            float mn = fmaxf(m_r[r], mx);
            alpha[r] = exp2f((m_r[r] - mn) * L2E);
            m_r[r] = mn;
            float rs = 0.f;
#pragma unroll
            for (int n = 0; n < 4; ++n) {
                float p = exp2f((s[n][r] - mn) * L2E);
                s[n][r] = p;
                rs += p;
            }
            rs += __shfl_xor(rs, 1);
            rs += __shfl_xor(rs, 2);
            rs += __shfl_xor(rs, 4);
            rs += __shfl_xor(rs, 8);
            l_r[r] = l_r[r] * alpha[r] + rs;
        }
#pragma unroll
        for (int dn = 0; dn < 4; ++dn)
#pragma unroll
            for (int r = 0; r < 4; ++r) accy[dn][r] *= alpha[r];
        {
            int colb = lane & 15;
            int rowb = w * 16 + (lane >> 4) * 4;
#pragma unroll
            for (int n = 0; n < 4; ++n) {
                int key = n * 16 + colb;
                int s8 = key >> 3, kr = key & 7;
#pragma unroll
                for (int r = 0; r < 4; ++r) {
                    int row = rowb + r;
                    sP[row * 64 + (((s8 ^ (row & 7)) << 3) | kr)] = f2bf(s[n][r]);
                }
            }
        }
        // P rows are written & read by the same wave only: no barrier needed.
        bf16x8 pa[2];
        {
            int prow = w * 16 + (lane & 15);
#pragma unroll
            for (int kk = 0; kk < 2; ++kk) {
                int sl = kk * 4 + (lane >> 4);
                pa[kk] = *(const bf16x8*)&sP[prow * 64 + ((sl ^ (prow & 7)) << 3)];
            }
        }
#pragma unroll
        for (int dn = 0; dn < 4; ++dn) {
            int vrow = dn * 16 + (lane & 15);
#pragma unroll
            for (int kk = 0; kk < 2; ++kk) {
                int sl = kk * 4 + (lane >> 4);
                bf16x8 vb = *(const bf16x8*)&sV[vrow * 64 + ((sl ^ (vrow & 7)) << 3)];
                accy[dn] = MFMA16(pa[kk], vb, accy[dn]);
            }
        }
    }
    {
        int rowb = q0 + w * 16 + (lane >> 4) * 4;
        int colb = h * 64 + (lane & 15);
#pragma unroll
        for (int r = 0; r < 4; ++r) {
            float inv = 1.0f / l_r[r];
#pragma unroll
            for (int dn = 0; dn < 4; ++dn)
                yb[(size_t)(b * 1024 + rowb + r) * 1024 + colb + dn * 16] = f2bf(accy[dn][r] * inv);
        }
    }
}

// ---------------- out projection: (8192x1024) x (1024x1024)^T, bf16 ----------------
__global__ __launch_bounds__(256) void proj_gemm(const u16* __restrict__ yb, const u16* __restrict__ wpb,
                                                 float* __restrict__ out) {
    __shared__ u16 As[128 * 32], Bs[128 * 32];
    const int mb = blockIdx.x >> 3, nb = blockIdx.x & 7;
    const int m0 = mb * 128, n0 = nb * 128;
    const int tid = threadIdx.x, lane = tid & 63, w = tid >> 6;
    const int wr = w >> 1, wc = w & 1;
    const int srow = tid >> 1, skc = (tid & 1) << 4;
    const u16* pa = yb + (m0 + srow) * 1024 + skc;
    const u16* pb = wpb + (n0 + srow) * 1024 + skc;
    const int s0 = skc >> 3;
    const int wA0 = srow * 32 + (((s0    ) ^ (srow & 3)) << 3);
    const int wA1 = srow * 32 + (((s0 + 1) ^ (srow & 3)) << 3);
    f32x4 acc[4][4] = {};
    for (int k0 = 0; k0 < 1024; k0 += 32) {
        *(bf16x8*)&As[wA0] = *(const bf16x8*)pa;
        *(bf16x8*)&As[wA1] = *(const bf16x8*)(pa + 8);
        *(bf16x8*)&Bs[wA0] = *(const bf16x8*)pb;
        *(bf16x8*)&Bs[wA1] = *(const bf16x8*)(pb + 8);
        pa += 32; pb += 32;
        __syncthreads();
        const int rsl = lane >> 4;
        bf16x8 af[4];
#pragma unroll
        for (int m = 0; m < 4; ++m) {
            int row = wr * 64 + m * 16 + (lane & 15);
            af[m] = *(const bf16x8*)&As[row * 32 + ((rsl ^ (row & 3)) << 3)];
        }
#pragma unroll
        for (int n = 0; n < 4; ++n) {
            int row = wc * 64 + n * 16 + (lane & 15);
            bf16x8 bf_ = *(const bf16x8*)&Bs[row * 32 + ((rsl ^ (row & 3)) << 3)];
#pragma unroll
            for (int m = 0; m < 4; ++m) acc[m][n] = MFMA16(af[m], bf_, acc[m][n]);
        }
        __syncthreads();
    }
#pragma unroll
    for (int m = 0; m < 4; ++m) {
        int rowb = m0 + wr * 64 + m * 16 + (lane >> 4) * 4;
#pragma unroll
        for (int n = 0; n < 4; ++n) {
            int col = n0 + wc * 64 + n * 16 + (lane & 15);
#pragma unroll
            for (int r = 0; r < 4; ++r) out[(size_t)(rowb + r) * 1024 + col] = acc[m][n][r];
        }
    }
}

extern "C" void kernel_launch(void* const* d_in, const int* in_sizes, int n_in,
                              void* d_out, int out_size, void* d_ws, size_t ws_size,
                              hipStream_t stream) {
    const float* x  = (const float*)d_in[0];
    const float* Wa = (const float*)d_in[1];
    const float* Wp = (const float*)d_in[2];
    float* out = (float*)d_out;
    char* ws = (char*)d_ws;
    size_t off = 0;
    float* qkv = (float*)(ws + off); off += (size_t)8192 * 3072 * 4;   // 96 MB
    u16* qh  = (u16*)(ws + off); off += 16777216;
    u16* ql  = (u16*)(ws + off); off += 16777216;
    u16* kh  = (u16*)(ws + off); off += 16777216;
    u16* kl  = (u16*)(ws + off); off += 16777216;
    u16* vt  = (u16*)(ws + off); off += 16777216;
    u16* yb  = (u16*)(ws + off); off += 16777216;
    u16* xh  = (u16*)(ws + off); off += 16777216;
    u16* xl  = (u16*)(ws + off); off += 16777216;
    u16* wah = (u16*)(ws + off); off += 6291456;
    u16* wal = (u16*)(ws + off); off += 6291456;
    u16* wpb = (u16*)(ws + off); off += 2097152;

    split_kernel<<<8192, 256, 0, stream>>>(x, xh, xl, 8192 * 1024 / 4);
    split_kernel<<<3072, 256, 0, stream>>>(Wa, wah, wal, 3072 * 1024 / 4);
    cvt_kernel<<<1024, 256, 0, stream>>>(Wp, wpb, 1024 * 1024 / 4);
    qkv_gemm<<<1536, 256, 0, stream>>>(xh, xl, wah, wal, qkv);
    rotary_split<<<32768, 256, 0, stream>>>(qkv, qh, ql, kh, kl, vt);
    attn_kernel<<<2048, 256, 0, stream>>>(qh, ql, kh, kl, vt, yb);
    proj_gemm<<<512, 256, 0, stream>>>(yb, Wp ? wpb : wpb, out);
}

// Round 3
// 375.278 us; speedup vs baseline: 1.3487x; 1.3487x over previous
//
#include <hip/hip_runtime.h>

typedef __attribute__((ext_vector_type(8))) short v8s;
typedef __attribute__((ext_vector_type(8))) _Float16 f16x8;
typedef __attribute__((ext_vector_type(4))) _Float16 f16x4;
typedef __attribute__((ext_vector_type(4))) float f32x4;
typedef unsigned short u16;

#define MFMAH(a,b,c) __builtin_amdgcn_mfma_f32_16x16x32_f16((a),(b),(c),0,0,0)
#define L2E 1.4426950408889634f

__device__ __forceinline__ u16 f2h(float f) {
    _Float16 h = (_Float16)f;
    return __builtin_bit_cast(u16, h);
}

__device__ __forceinline__ void gload16(const u16* g, u16* l) {
    __builtin_amdgcn_global_load_lds((const __attribute__((address_space(1))) void*)g,
                                     (__attribute__((address_space(3))) void*)l, 16, 0, 0);
}

// Stage a 128x64 f16 tile (row stride 1024 elems) into LDS.
// LDS dest is linear (gload_lds writes base+lane*16); the XOR slot-swizzle
// (slot' = slot ^ (row&7)) is applied by permuting the per-lane GLOBAL source
// (G21: both-sides-or-neither). Wave w stages rows [32w, 32w+32).
__device__ __forceinline__ void stage_tile(const u16* __restrict__ base, u16* lds, int w, int lane) {
    const int rsub = lane >> 3;
    const int s_org = (lane & 7) ^ rsub;
#pragma unroll
    for (int i = 0; i < 4; ++i) {
        const u16* src = base + (size_t)(32 * w + 8 * i + rsub) * 1024 + 8 * s_org;
        gload16(src, lds + (32 * w + 8 * i) * 64);
    }
}

// ---------------- elementwise converts ----------------
__global__ __launch_bounds__(256) void split16_kernel(const float* __restrict__ in,
                                                      u16* __restrict__ hi, u16* __restrict__ lo, int n4) {
    int i = blockIdx.x * 256 + threadIdx.x;
    if (i >= n4) return;
    f32x4 v = ((const f32x4*)in)[i];
    f16x4 h, l;
#pragma unroll
    for (int j = 0; j < 4; ++j) {
        _Float16 hh = (_Float16)v[j];
        h[j] = hh;
        l[j] = (_Float16)(v[j] - (float)hh);
    }
    ((f16x4*)hi)[i] = h;
    ((f16x4*)lo)[i] = l;
}

__global__ __launch_bounds__(256) void cvt16_kernel(const float* __restrict__ in, u16* __restrict__ out, int n4) {
    int i = blockIdx.x * 256 + threadIdx.x;
    if (i >= n4) return;
    f32x4 v = ((const f32x4*)in)[i];
    f16x4 h;
#pragma unroll
    for (int j = 0; j < 4; ++j) h[j] = (_Float16)v[j];
    ((f16x4*)out)[i] = h;
}

// ---------------- qkv GEMM: (8192x1024) x (3072x1024)^T ----------------
// q,k columns: acc = xh*w + xl*w (exact-x * fp16-w). v columns: xh*w only.
__global__ __launch_bounds__(256) void qkv_gemm2(const u16* __restrict__ xh, const u16* __restrict__ xl,
                                                 const u16* __restrict__ wf, float* __restrict__ qkv) {
    __shared__ u16 sAh[8192], sAl[8192], sB[8192];
    const int bid = blockIdx.x;
    const int swz = (bid & 7) * 192 + (bid >> 3);   // 1536 = 8*192, bijective XCD swizzle
    const int mb = swz / 24, nb = swz % 24;
    const int m0 = mb * 128, n0 = nb * 128;
    const bool lo = (nb < 16);                      // q,k thirds get the lo term
    const int tid = threadIdx.x, lane = tid & 63, w = tid >> 6;
    const int wr = w >> 1, wc = w & 1;
    const int fr = lane & 15, fq = lane >> 4;
    const u16* pa = xh + (size_t)m0 * 1024;
    const u16* pal = xl + (size_t)m0 * 1024;
    const u16* pb = wf + (size_t)n0 * 1024;
    f32x4 acc[4][4] = {};
    for (int k0 = 0; k0 < 1024; k0 += 64) {
        stage_tile(pa + k0, sAh, w, lane);
        stage_tile(pb + k0, sB, w, lane);
        if (lo) stage_tile(pal + k0, sAl, w, lane);
        __syncthreads();
#pragma unroll
        for (int kk = 0; kk < 2; ++kk) {
            f16x8 ah[4], al[4], bb[4];
#pragma unroll
            for (int m = 0; m < 4; ++m) {
                int row = wr * 64 + m * 16 + fr;
                int off = row * 64 + ((((kk * 4 + fq)) ^ (fr & 7)) << 3);
                ah[m] = *(const f16x8*)&sAh[off];
                if (lo) al[m] = *(const f16x8*)&sAl[off];
            }
#pragma unroll
            for (int n = 0; n < 4; ++n) {
                int row = wc * 64 + n * 16 + fr;
                bb[n] = *(const f16x8*)&sB[row * 64 + ((((kk * 4 + fq)) ^ (fr & 7)) << 3)];
            }
#pragma unroll
            for (int n = 0; n < 4; ++n)
#pragma unroll
                for (int m = 0; m < 4; ++m) {
                    acc[m][n] = MFMAH(ah[m], bb[n], acc[m][n]);
                    if (lo) acc[m][n] = MFMAH(al[m], bb[n], acc[m][n]);
                }
        }
        __syncthreads();
    }
#pragma unroll
    for (int m = 0; m < 4; ++m) {
        int rowb = m0 + wr * 64 + m * 16 + fq * 4;
#pragma unroll
        for (int n = 0; n < 4; ++n) {
            int col = n0 + wc * 64 + n * 16 + fr;
#pragma unroll
            for (int r = 0; r < 4; ++r)
                qkv[(size_t)(rowb + r) * 3072 + col] = acc[m][n][r];
        }
    }
}

// ---------------- rotary (cos/sin of q), fp16 outputs, transpose v ----------------
__global__ __launch_bounds__(256) void rotary_kernel(const float* __restrict__ qkv,
                                                     u16* __restrict__ qf, u16* __restrict__ kf,
                                                     u16* __restrict__ vt) {
    int rid = blockIdx.x * 4 + (threadIdx.x >> 6);
    int lane = threadIdx.x & 63;
    int b = rid >> 14, h = (rid >> 10) & 15, t = rid & 1023;
    const float* base = qkv + (size_t)(b * 1024 + t) * 3072 + h * 64 + lane;
    float q = base[0], k = base[1024], v = base[2048];
    float s, c;
    sincosf(q, &s, &c);
    int src = (lane < 32) ? (2 * lane + 1) : (2 * lane - 64);
    float qp = __shfl(q, src);
    float kp = __shfl(k, src);
    float rq = (lane < 32) ? -qp : qp;
    float rk = (lane < 32) ? -kp : kp;
    float q2 = q * c + rq * s;
    float k2 = k * c + rk * s;
    size_t oi = (size_t)((b * 16 + h) * 1024 + t) * 64 + lane;
    qf[oi] = f2h(q2);
    kf[oi] = f2h(k2);
    vt[(size_t)((b * 16 + h) * 64 + lane) * 1024 + t] = f2h(v);
}

// ---------------- flash attention, causal, scale=1.0, fp16 ----------------
__global__ __launch_bounds__(256) void attn_kernel(const u16* __restrict__ qf, const u16* __restrict__ kf,
                                                   const u16* __restrict__ vt, u16* __restrict__ yb) {
    __shared__ u16 sQ[4096], sK[4096], sV[4096], sP[4096];
    const int bh = blockIdx.x >> 4, qt = blockIdx.x & 15;
    const int b = bh >> 4, h = bh & 15;
    const int tid = threadIdx.x, lane = tid & 63, w = tid >> 6;
    const int q0 = qt * 64;
    const int fr = lane & 15, fq = lane >> 4;
    const int srow = tid >> 2, sc = (tid & 3) << 4;
    const int ss0 = sc >> 3;
    const int wr0 = srow * 64 + (((ss0    ) ^ (srow & 7)) << 3);
    const int wr1 = srow * 64 + (((ss0 + 1) ^ (srow & 7)) << 3);
    {
        const u16* g = qf + (size_t)(bh * 1024 + q0 + srow) * 64 + sc;
        *(v8s*)&sQ[wr0] = *(const v8s*)g;
        *(v8s*)&sQ[wr1] = *(const v8s*)(g + 8);
    }
    __syncthreads();
    f16x8 qfr[2];
    {
        int row = w * 16 + fr;
#pragma unroll
        for (int kk = 0; kk < 2; ++kk) {
            int sl = kk * 4 + fq;
            qfr[kk] = *(const f16x8*)&sQ[row * 64 + ((sl ^ (row & 7)) << 3)];
        }
    }
    f32x4 accy[4] = {};
    float m_r[4], l_r[4];
#pragma unroll
    for (int r = 0; r < 4; ++r) { m_r[r] = -1e30f; l_r[r] = 0.f; }
    const u16* gk = kf + (size_t)bh * 65536 + srow * 64 + sc;
    const u16* gv = vt + (size_t)(bh * 64 + srow) * 1024 + sc;

    for (int kt = 0; kt <= qt; ++kt) {
        __syncthreads();
        {
            const u16* a  = gk + kt * 4096;
            const u16* vg = gv + kt * 64;
            *(v8s*)&sK[wr0] = *(const v8s*)a;
            *(v8s*)&sK[wr1] = *(const v8s*)(a + 8);
            *(v8s*)&sV[wr0] = *(const v8s*)vg;
            *(v8s*)&sV[wr1] = *(const v8s*)(vg + 8);
        }
        __syncthreads();
        f32x4 s[4] = {};
#pragma unroll
        for (int n = 0; n < 4; ++n) {
            int krow = n * 16 + fr;
#pragma unroll
            for (int kk = 0; kk < 2; ++kk) {
                int sl = kk * 4 + fq;
                f16x8 kb = *(const f16x8*)&sK[krow * 64 + ((sl ^ (krow & 7)) << 3)];
                s[n] = MFMAH(qfr[kk], kb, s[n]);
            }
        }
        if (kt == qt) {
            int rowb = w * 16 + fq * 4;
#pragma unroll
            for (int n = 0; n < 4; ++n)
#pragma unroll
                for (int r = 0; r < 4; ++r)
                    if (n * 16 + fr > rowb + r) s[n][r] = -1e30f;
        }
        float alpha[4];
#pragma unroll
        for (int r = 0; r < 4; ++r) {
            float mx = fmaxf(fmaxf(s[0][r], s[1][r]), fmaxf(s[2][r], s[3][r]));
            mx = fmaxf(mx, __shfl_xor(mx, 1));
            mx = fmaxf(mx, __shfl_xor(mx, 2));
            mx = fmaxf(mx, __shfl_xor(mx, 4));
            mx = fmaxf(mx, __shfl_xor(mx, 8));
            float mn = fmaxf(m_r[r], mx);
            alpha[r] = exp2f((m_r[r] - mn) * L2E);
            m_r[r] = mn;
            float rs = 0.f;
#pragma unroll
            for (int n = 0; n < 4; ++n) {
                float p = exp2f((s[n][r] - mn) * L2E);
                s[n][r] = p;
                rs += p;
            }
            rs += __shfl_xor(rs, 1);
            rs += __shfl_xor(rs, 2);
            rs += __shfl_xor(rs, 4);
            rs += __shfl_xor(rs, 8);
            l_r[r] = l_r[r] * alpha[r] + rs;
        }
#pragma unroll
        for (int dn = 0; dn < 4; ++dn)
#pragma unroll
            for (int r = 0; r < 4; ++r) accy[dn][r] *= alpha[r];
        {
            int rowb = w * 16 + fq * 4;
#pragma unroll
            for (int n = 0; n < 4; ++n) {
                int key = n * 16 + fr;
                int s8 = key >> 3, kr = key & 7;
#pragma unroll
                for (int r = 0; r < 4; ++r) {
                    int row = rowb + r;
                    sP[row * 64 + (((s8 ^ (row & 7)) << 3) | kr)] = f2h(s[n][r]);
                }
            }
        }
        // P rows written & read by the same wave only: no barrier needed.
        f16x8 pa[2];
        {
            int prow = w * 16 + fr;
#pragma unroll
            for (int kk = 0; kk < 2; ++kk) {
                int sl = kk * 4 + fq;
                pa[kk] = *(const f16x8*)&sP[prow * 64 + ((sl ^ (prow & 7)) << 3)];
            }
        }
#pragma unroll
        for (int dn = 0; dn < 4; ++dn) {
            int vrow = dn * 16 + fr;
#pragma unroll
            for (int kk = 0; kk < 2; ++kk) {
                int sl = kk * 4 + fq;
                f16x8 vb = *(const f16x8*)&sV[vrow * 64 + ((sl ^ (vrow & 7)) << 3)];
                accy[dn] = MFMAH(pa[kk], vb, accy[dn]);
            }
        }
    }
    {
        int rowb = q0 + w * 16 + fq * 4;
        int colb = h * 64 + fr;
#pragma unroll
        for (int r = 0; r < 4; ++r) {
            float inv = 1.0f / l_r[r];
#pragma unroll
            for (int dn = 0; dn < 4; ++dn)
                yb[(size_t)(b * 1024 + rowb + r) * 1024 + colb + dn * 16] = f2h(accy[dn][r] * inv);
        }
    }
}

// ---------------- out projection: (8192x1024) x (1024x1024)^T, fp16 ----------------
__global__ __launch_bounds__(256) void proj_gemm2(const u16* __restrict__ yb, const u16* __restrict__ wpb,
                                                  float* __restrict__ out) {
    __shared__ u16 sA[8192], sB[8192];
    const int bid = blockIdx.x;
    const int swz = (bid & 7) * 64 + (bid >> 3);    // 512 = 8*64
    const int mb = swz >> 3, nb = swz & 7;
    const int m0 = mb * 128, n0 = nb * 128;
    const int tid = threadIdx.x, lane = tid & 63, w = tid >> 6;
    const int wr = w >> 1, wc = w & 1;
    const int fr = lane & 15, fq = lane >> 4;
    const u16* pa = yb + (size_t)m0 * 1024;
    const u16* pb = wpb + (size_t)n0 * 1024;
    f32x4 acc[4][4] = {};
    for (int k0 = 0; k0 < 1024; k0 += 64) {
        stage_tile(pa + k0, sA, w, lane);
        stage_tile(pb + k0, sB, w, lane);
        __syncthreads();
#pragma unroll
        for (int kk = 0; kk < 2; ++kk) {
            f16x8 af[4], bb[4];
#pragma unroll
            for (int m = 0; m < 4; ++m) {
                int row = wr * 64 + m * 16 + fr;
                af[m] = *(const f16x8*)&sA[row * 64 + ((((kk * 4 + fq)) ^ (fr & 7)) << 3)];
            }
#pragma unroll
            for (int n = 0; n < 4; ++n) {
                int row = wc * 64 + n * 16 + fr;
                bb[n] = *(const f16x8*)&sB[row * 64 + ((((kk * 4 + fq)) ^ (fr & 7)) << 3)];
            }
#pragma unroll
            for (int n = 0; n < 4; ++n)
#pragma unroll
                for (int m = 0; m < 4; ++m) acc[m][n] = MFMAH(af[m], bb[n], acc[m][n]);
        }
        __syncthreads();
    }
#pragma unroll
    for (int m = 0; m < 4; ++m) {
        int rowb = m0 + wr * 64 + m * 16 + fq * 4;
#pragma unroll
        for (int n = 0; n < 4; ++n) {
            int col = n0 + wc * 64 + n * 16 + fr;
#pragma unroll
            for (int r = 0; r < 4; ++r) out[(size_t)(rowb + r) * 1024 + col] = acc[m][n][r];
        }
    }
}

extern "C" void kernel_launch(void* const* d_in, const int* in_sizes, int n_in,
                              void* d_out, int out_size, void* d_ws, size_t ws_size,
                              hipStream_t stream) {
    const float* x  = (const float*)d_in[0];
    const float* Wa = (const float*)d_in[1];
    const float* Wp = (const float*)d_in[2];
    float* out = (float*)d_out;
    char* ws = (char*)d_ws;
    size_t off = 0;
    float* qkv = (float*)(ws + off); off += (size_t)8192 * 3072 * 4;   // 96 MB
    u16* xh  = (u16*)(ws + off); off += 16777216;
    u16* xl  = (u16*)(ws + off); off += 16777216;
    u16* wf  = (u16*)(ws + off); off += 6291456;
    u16* wpb = (u16*)(ws + off); off += 2097152;
    u16* qf  = (u16*)(ws + off); off += 16777216;
    u16* kf  = (u16*)(ws + off); off += 16777216;
    u16* vt  = (u16*)(ws + off); off += 16777216;
    u16* yb  = (u16*)(ws + off); off += 16777216;

    split16_kernel<<<8192, 256, 0, stream>>>(x, xh, xl, 8192 * 1024 / 4);
    cvt16_kernel<<<3072, 256, 0, stream>>>(Wa, wf, 3072 * 1024 / 4);
    cvt16_kernel<<<1024, 256, 0, stream>>>(Wp, wpb, 1024 * 1024 / 4);
    qkv_gemm2<<<1536, 256, 0, stream>>>(xh, xl, wf, qkv);
    rotary_kernel<<<32768, 256, 0, stream>>>(qkv, qf, kf, vt);
    attn_kernel<<<2048, 256, 0, stream>>>(qf, kf, vt, yb);
    proj_gemm2<<<512, 256, 0, stream>>>(yb, wpb, out);
}